// Round 1
// baseline (2115.053 us; speedup 1.0000x reference)
//
#include <hip/hip_runtime.h>

typedef short short8 __attribute__((ext_vector_type(8)));
typedef float f4 __attribute__((ext_vector_type(4)));
typedef _Float16 h2 __attribute__((ext_vector_type(2)));

#define HD 256
#define ED 300
#define EP 320
#define TH 768
#define NS 1024
#define LW 64

__device__ __forceinline__ unsigned short f2bf(float f) {
    unsigned int u = __float_as_uint(f);
    u = (u + 0x7FFFu + ((u >> 16) & 1u)) >> 16;
    return (unsigned short)u;
}
__device__ __forceinline__ float bf2f(unsigned short s) {
    return __uint_as_float(((unsigned int)s) << 16);
}
__device__ __forceinline__ float sigm(float x) { return 1.f / (1.f + __expf(-x)); }
__device__ __forceinline__ float tanh_(float x) {
    x = fminf(fmaxf(x, -15.f), 15.f);
    float e = __expf(2.f * x);
    return (e - 1.f) / (e + 1.f);
}
__device__ __forceinline__ unsigned int pack_h2(float a, float b) {
    h2 p; p.x = (_Float16)a; p.y = (_Float16)b;
    return __builtin_bit_cast(unsigned int, p);
}
__device__ __forceinline__ h2 bc_h2(unsigned int u) { return __builtin_bit_cast(h2, u); }

__device__ __forceinline__ void load16bf(const unsigned short* p, float* o) {
    uint4 a = *(const uint4*)p;
    uint4 b = *(const uint4*)(p + 8);
    o[0] = bf2f((unsigned short)(a.x & 0xffff)); o[1] = bf2f((unsigned short)(a.x >> 16));
    o[2] = bf2f((unsigned short)(a.y & 0xffff)); o[3] = bf2f((unsigned short)(a.y >> 16));
    o[4] = bf2f((unsigned short)(a.z & 0xffff)); o[5] = bf2f((unsigned short)(a.z >> 16));
    o[6] = bf2f((unsigned short)(a.w & 0xffff)); o[7] = bf2f((unsigned short)(a.w >> 16));
    o[8] = bf2f((unsigned short)(b.x & 0xffff)); o[9] = bf2f((unsigned short)(b.x >> 16));
    o[10] = bf2f((unsigned short)(b.y & 0xffff)); o[11] = bf2f((unsigned short)(b.y >> 16));
    o[12] = bf2f((unsigned short)(b.z & 0xffff)); o[13] = bf2f((unsigned short)(b.z >> 16));
    o[14] = bf2f((unsigned short)(b.w & 0xffff)); o[15] = bf2f((unsigned short)(b.w >> 16));
}

// ---------------- prep: weight conversions, Dq table, topic vector ----------------
__global__ void k_prep(const float* __restrict__ W, const float* __restrict__ U,
                       const float* __restrict__ Wih, const float* __restrict__ Whh,
                       const float* __restrict__ q, const float* __restrict__ Dm,
                       const float* __restrict__ DT, const float* __restrict__ mlpW,
                       const float* __restrict__ mlpb,
                       unsigned short* __restrict__ Wb, unsigned short* __restrict__ Ub,
                       unsigned short* __restrict__ Wihb, _Float16* __restrict__ Whh_h,
                       float* __restrict__ Dq, float* __restrict__ tv) {
    int bid = blockIdx.x, tid = threadIdx.x;
    if (bid < 768) {
        int r = bid;
        for (int j = tid; j < EP; j += 256)
            Wb[r * EP + j] = (j < ED) ? f2bf(W[r * ED + j]) : (unsigned short)0;
        for (int j = tid; j < HD; j += 256) {
            Ub[r * HD + j] = f2bf(U[r * HD + j]);
            Wihb[r * HD + j] = f2bf(Wih[r * HD + j]);
            Whh_h[r * HD + j] = (_Float16)Whh[r * HD + j];
        }
    } else if (bid < 798) {
        int idx = bid - 768;
        int d = idx / 3, part = idx - d * 3;
        int n = part * 256 + tid;
        float s = 0.f;
        for (int h = 0; h < HD; ++h) s += Dm[n * HD + h] * q[d * HD + h];
        Dq[d * TH + n] = s;
    } else {
        if (tid < HD) {
            float s = 0.f;
            for (int k = 0; k < 100; ++k) s += mlpW[tid * 100 + k] * DT[k];
            tv[tid] = tanh_(s + mlpb[tid]);
        }
    }
}

// ---------------- phase B: pre[m][n] = (x @ W^T)[m][n] + Dq_table[dep(m)][n] + b[n] ----------------
// Tile: A = W rows (768, all), B = 32 gathered x rows per block. D[m=W-row][n=x-row].
__launch_bounds__(256, 2)
__global__ void k_phaseB(const int* __restrict__ sIdx, const int* __restrict__ depT,
                         const float* __restrict__ emb, const unsigned short* __restrict__ Wb,
                         const float* __restrict__ Dq, const float* __restrict__ bias,
                         unsigned short* __restrict__ pre) {
    __shared__ float dq_s[10 * 772];
    __shared__ float b_s[TH];
    __shared__ int dep_s[32];
    __shared__ int idx_s[32];
    int tid = threadIdx.x;
    int c0 = blockIdx.x * 32;
    for (int i = tid; i < 10 * 768; i += 256) {
        int d = i / 768, n = i - d * 768;
        dq_s[d * 772 + n] = Dq[i];
    }
    for (int i = tid; i < TH; i += 256) b_s[i] = bias[i];
    if (tid < 32) {
        int m = c0 + tid;
        idx_s[tid] = sIdx[m];
        int l = m & 63, s = m >> 6;
        dep_s[tid] = (l == 63) ? 9 : depT[s * 63 + l];
    }
    __syncthreads();

    int lane = tid & 63;
    int w = tid >> 6;
    int quad = lane >> 4, l16 = lane & 15;

    const float* xr0 = emb + (long)idx_s[l16] * ED;
    const float* xr1 = emb + (long)idx_s[16 + l16] * ED;

    f4 acc[2][12];
#pragma unroll
    for (int cs = 0; cs < 2; ++cs)
#pragma unroll
        for (int ms = 0; ms < 12; ++ms) acc[cs][ms] = (f4){0.f, 0.f, 0.f, 0.f};

    const unsigned short* wbase = Wb + (w * 192 + l16) * EP;

#pragma unroll
    for (int kt = 0; kt < 10; ++kt) {
        int k0 = kt * 32 + quad * 8;
        short8 bf[2];
#pragma unroll
        for (int cs = 0; cs < 2; ++cs) {
            const float* xr = cs ? xr1 : xr0;
            float xv[8];
            if (k0 + 8 <= ED) {
                float4 f0 = *(const float4*)(xr + k0);
                float4 f1 = *(const float4*)(xr + k0 + 4);
                xv[0] = f0.x; xv[1] = f0.y; xv[2] = f0.z; xv[3] = f0.w;
                xv[4] = f1.x; xv[5] = f1.y; xv[6] = f1.z; xv[7] = f1.w;
            } else {
#pragma unroll
                for (int j = 0; j < 8; ++j) xv[j] = (k0 + j < ED) ? xr[k0 + j] : 0.f;
            }
            short8 t;
#pragma unroll
            for (int j = 0; j < 8; ++j) t[j] = (short)f2bf(xv[j]);
            bf[cs] = t;
        }
#pragma unroll
        for (int ms = 0; ms < 12; ++ms) {
            short8 af = *(const short8*)(wbase + ms * 16 * EP + k0);
            acc[0][ms] = __builtin_amdgcn_mfma_f32_16x16x32_bf16(af, bf[0], acc[0][ms], 0, 0, 0);
            acc[1][ms] = __builtin_amdgcn_mfma_f32_16x16x32_bf16(af, bf[1], acc[1][ms], 0, 0, 0);
        }
    }

#pragma unroll
    for (int cs = 0; cs < 2; ++cs) {
        int xr = c0 + cs * 16 + l16;
        int dep = dep_s[cs * 16 + l16];
        unsigned short* prow = pre + (long)xr * TH;
#pragma unroll
        for (int ms = 0; ms < 12; ++ms) {
            int ncol = w * 192 + ms * 16 + quad * 4;
            f4 dq4 = *(const f4*)&dq_s[dep * 772 + ncol];
            f4 b4 = *(const f4*)&b_s[ncol];
            unsigned int lo = (unsigned int)f2bf(acc[cs][ms][0] + dq4[0] + b4[0]) |
                              ((unsigned int)f2bf(acc[cs][ms][1] + dq4[1] + b4[1]) << 16);
            unsigned int hi = (unsigned int)f2bf(acc[cs][ms][2] + dq4[2] + b4[2]) |
                              ((unsigned int)f2bf(acc[cs][ms][3] + dq4[3] + b4[3]) << 16);
            uint2 v; v.x = lo; v.y = hi;
            *(uint2*)(prow + ncol) = v;
        }
    }
}

// ---------------- phase C: per-sentence tree scan (16 sentences per block) + gi epilogue ----------------
__launch_bounds__(256)
__global__ void k_phaseC(const unsigned short* __restrict__ pre,
                         const unsigned short* __restrict__ Ub,
                         const unsigned short* __restrict__ Wihb,
                         const float* __restrict__ bih,
                         float* __restrict__ gi) {
    __shared__ __align__(16) unsigned int hfr[8][64][4]; // bf16 A-fragments of h: [kt][lane][dword]
    __shared__ float tot[16 * 772];
    int tid = threadIdx.x;
    int s0 = blockIdx.x * 16;
    int lane = tid & 63, w = tid >> 6, quad = lane >> 4, l16 = lane & 15;
    int si = tid & 15, jg = tid >> 4;
    int j0 = jg * 16;

    float hc[16];

    // leaf: h = tanh(sigmoid(i) * tanh(u)), i/u from pre[s][63][256:768]
    {
        const unsigned short* prow = pre + ((long)(s0 + si) * LW + 63) * TH;
        float iv[16], uv[16];
        load16bf(prow + 256 + j0, iv);
        load16bf(prow + 512 + j0, uv);
#pragma unroll
        for (int r = 0; r < 16; ++r) hc[r] = tanh_(sigm(iv[r]) * tanh_(uv[r]));
    }
#pragma unroll
    for (int r = 0; r < 16; r += 2) {
        int k = j0 + r;
        hfr[k >> 5][si + 16 * ((k >> 3) & 3)][(k & 7) >> 1] =
            (unsigned int)f2bf(hc[r]) | ((unsigned int)f2bf(hc[r + 1]) << 16);
    }
    __syncthreads();

    for (int step = 0; step < 63; ++step) {
        int l = 62 - step;
        f4 acc[12];
#pragma unroll
        for (int nt = 0; nt < 12; ++nt) acc[nt] = (f4){0.f, 0.f, 0.f, 0.f};
        const unsigned short* ub = Ub + (w * 192 + l16) * HD;
#pragma unroll
        for (int kt = 0; kt < 8; ++kt) {
            short8 af = *(const short8*)&hfr[kt][lane][0];
            int k0 = kt * 32 + quad * 8;
#pragma unroll
            for (int nt = 0; nt < 12; ++nt) {
                short8 bfv = *(const short8*)(ub + nt * 16 * HD + k0);
                acc[nt] = __builtin_amdgcn_mfma_f32_16x16x32_bf16(af, bfv, acc[nt], 0, 0, 0);
            }
        }
#pragma unroll
        for (int nt = 0; nt < 12; ++nt) {
            int n = w * 192 + nt * 16 + l16;
#pragma unroll
            for (int r = 0; r < 4; ++r) tot[(quad * 4 + r) * 772 + n] = acc[nt][r];
        }
        __syncthreads();
        {
            const unsigned short* prow = pre + ((long)(s0 + si) * LW + l) * TH;
            const float* trow = tot + si * 772;
            float pf[16], pi_[16], pu[16];
            load16bf(prow + j0, pf);
            load16bf(prow + 256 + j0, pi_);
            load16bf(prow + 512 + j0, pu);
#pragma unroll
            for (int r = 0; r < 16; ++r) {
                float tf = trow[j0 + r] + pf[r];
                float ti = trow[256 + j0 + r] + pi_[r];
                float tu = trow[512 + j0 + r] + pu[r];
                hc[r] = tanh_(sigm(ti) * tanh_(tu) + sigm(tf) * hc[r]);
            }
        }
#pragma unroll
        for (int r = 0; r < 16; r += 2) {
            int k = j0 + r;
            hfr[k >> 5][si + 16 * ((k >> 3) & 3)][(k & 7) >> 1] =
                (unsigned int)f2bf(hc[r]) | ((unsigned int)f2bf(hc[r + 1]) << 16);
        }
        __syncthreads();
    }

    // gi[s] = Wih @ sv_s + bih
    {
        f4 acc[12];
#pragma unroll
        for (int nt = 0; nt < 12; ++nt) acc[nt] = (f4){0.f, 0.f, 0.f, 0.f};
        const unsigned short* ub = Wihb + (w * 192 + l16) * HD;
#pragma unroll
        for (int kt = 0; kt < 8; ++kt) {
            short8 af = *(const short8*)&hfr[kt][lane][0];
            int k0 = kt * 32 + quad * 8;
#pragma unroll
            for (int nt = 0; nt < 12; ++nt) {
                short8 bfv = *(const short8*)(ub + nt * 16 * HD + k0);
                acc[nt] = __builtin_amdgcn_mfma_f32_16x16x32_bf16(af, bfv, acc[nt], 0, 0, 0);
            }
        }
#pragma unroll
        for (int nt = 0; nt < 12; ++nt) {
            int n = w * 192 + nt * 16 + l16;
            float bv = bih[n];
#pragma unroll
            for (int r = 0; r < 4; ++r)
                gi[(long)(s0 + quad * 4 + r) * TH + n] = acc[nt][r] + bv;
        }
    }
}

// ---------------- GRU: persistent single workgroup, 1024 sequential steps + head ----------------
__launch_bounds__(768)
__global__ void k_gru(const _Float16* __restrict__ Whh_h, const float* __restrict__ bhh,
                      const float* __restrict__ gi, const float* __restrict__ h0,
                      const float* __restrict__ tv,
                      const float* __restrict__ gateW, const float* __restrict__ gateU,
                      const float* __restrict__ gateb,
                      const float* __restrict__ outW, const float* __restrict__ outb,
                      float* __restrict__ out) {
    __shared__ __align__(16) unsigned int h2s[128]; // h as packed f16x2
    __shared__ float ghs[TH];
    __shared__ float hts[HD];
    __shared__ float sgs[512];
    __shared__ float vvs[HD];
    __shared__ float lg[8];

    int tid = threadIdx.x;
    uint4 wv[32];
    const uint4* wp = (const uint4*)(Whh_h + (long)tid * HD);
#pragma unroll
    for (int i = 0; i < 32; ++i) wv[i] = wp[i];
    float bh = bhh[tid];

    float hA = 0.f, hB = 0.f;
    if (tid < 128) {
        hA = h0[2 * tid];
        hB = h0[2 * tid + 1];
        h2s[tid] = pack_h2(hA, hB);
    }
    __syncthreads();

    for (int t = 0; t < NS; ++t) {
        // prefetch gi for the update threads
        float g_r0 = 0.f, g_r1 = 0.f, g_z0 = 0.f, g_z1 = 0.f, g_n0 = 0.f, g_n1 = 0.f;
        if (tid < 128) {
            const float* g = gi + (long)t * TH;
            int j = 2 * tid;
            g_r0 = g[j]; g_r1 = g[j + 1];
            g_z0 = g[256 + j]; g_z1 = g[257 + j];
            g_n0 = g[512 + j]; g_n1 = g[513 + j];
        }
        float a0 = 0.f, a1 = 0.f, a2 = 0.f, a3 = 0.f;
        const uint4* hp = (const uint4*)h2s;
#pragma unroll
        for (int i = 0; i < 32; ++i) {
            uint4 hv = hp[i];
            a0 = __builtin_amdgcn_fdot2(bc_h2(wv[i].x), bc_h2(hv.x), a0, false);
            a1 = __builtin_amdgcn_fdot2(bc_h2(wv[i].y), bc_h2(hv.y), a1, false);
            a2 = __builtin_amdgcn_fdot2(bc_h2(wv[i].z), bc_h2(hv.z), a2, false);
            a3 = __builtin_amdgcn_fdot2(bc_h2(wv[i].w), bc_h2(hv.w), a3, false);
        }
        ghs[tid] = (a0 + a1) + (a2 + a3) + bh;
        __syncthreads();
        if (tid < 128) {
            int j = 2 * tid;
            float r0 = sigm(g_r0 + ghs[j]);
            float r1 = sigm(g_r1 + ghs[j + 1]);
            float z0 = sigm(g_z0 + ghs[256 + j]);
            float z1 = sigm(g_z1 + ghs[257 + j]);
            float n0 = tanh_(g_n0 + r0 * ghs[512 + j]);
            float n1 = tanh_(g_n1 + r1 * ghs[513 + j]);
            hA = (1.f - z0) * n0 + z0 * hA;
            hB = (1.f - z1) * n1 + z1 * hB;
            h2s[tid] = pack_h2(hA, hB);
        }
        __syncthreads();
    }

    // head
    if (tid < 128) { hts[2 * tid] = hA; hts[2 * tid + 1] = hB; }
    __syncthreads();
    if (tid < 512) {
        float s = gateb[tid];
        for (int k = 0; k < HD; ++k)
            s += gateW[tid * HD + k] * hts[k] + gateU[tid * HD + k] * tv[k];
        sgs[tid] = sigm(s);
    }
    __syncthreads();
    if (tid < HD) vvs[tid] = tanh_(sgs[tid] * hts[tid] + sgs[256 + tid] * tv[tid]);
    __syncthreads();
    if (tid < 5) {
        float s = outb[tid];
        for (int k = 0; k < HD; ++k) s += outW[tid * HD + k] * vvs[k];
        lg[tid] = s;
    }
    __syncthreads();
    if (tid == 0) {
        float m = lg[0];
        for (int i = 1; i < 5; ++i) m = fmaxf(m, lg[i]);
        float e[5], sum = 0.f;
        for (int i = 0; i < 5; ++i) { e[i] = __expf(lg[i] - m); sum += e[i]; }
        for (int i = 0; i < 5; ++i) out[i] = e[i] / sum;
    }
}

extern "C" void kernel_launch(void* const* d_in, const int* in_sizes, int n_in,
                              void* d_out, int out_size, void* d_ws, size_t ws_size,
                              hipStream_t stream) {
    (void)in_sizes; (void)n_in; (void)out_size; (void)ws_size;
    const int* sIdx = (const int*)d_in[0];
    const int* depT = (const int*)d_in[1];
    const float* DT = (const float*)d_in[2];
    const float* h0 = (const float*)d_in[3];
    const float* emb = (const float*)d_in[4];
    const float* q = (const float*)d_in[5];
    const float* W = (const float*)d_in[6];
    const float* U = (const float*)d_in[7];
    const float* Dm = (const float*)d_in[8];
    const float* b = (const float*)d_in[9];
    const float* Wih = (const float*)d_in[10];
    const float* Whh = (const float*)d_in[11];
    const float* bih = (const float*)d_in[12];
    const float* bhh = (const float*)d_in[13];
    const float* gateW = (const float*)d_in[14];
    const float* gateU = (const float*)d_in[15];
    const float* gateb = (const float*)d_in[16];
    const float* mlpW = (const float*)d_in[17];
    const float* mlpb = (const float*)d_in[18];
    const float* outW = (const float*)d_in[19];
    const float* outb = (const float*)d_in[20];

    char* ws = (char*)d_ws;
    unsigned short* Wb = (unsigned short*)ws;        ws += 768 * 320 * 2;       // 491520
    unsigned short* Ub = (unsigned short*)ws;        ws += 768 * 256 * 2;       // 393216
    unsigned short* Wihb = (unsigned short*)ws;      ws += 768 * 256 * 2;       // 393216
    _Float16* Whh_h = (_Float16*)ws;                 ws += 768 * 256 * 2;       // 393216
    float* Dq = (float*)ws;                          ws += 10 * 768 * 4;        // 30720
    float* tv = (float*)ws;                          ws += 1024;                // 1024
    ws = (char*)d_ws + ((((size_t)(ws - (char*)d_ws)) + 4095) & ~(size_t)4095);
    unsigned short* pre = (unsigned short*)ws;       ws += (size_t)65536 * 768 * 2; // ~100.7 MB
    float* gi = (float*)ws;                          ws += (size_t)1024 * 768 * 4;  // 3 MB

    k_prep<<<dim3(799), dim3(256), 0, stream>>>(W, U, Wih, Whh, q, Dm, DT, mlpW, mlpb,
                                                Wb, Ub, Wihb, Whh_h, Dq, tv);
    k_phaseB<<<dim3(2048), dim3(256), 0, stream>>>(sIdx, depT, emb, Wb, Dq, b, pre);
    k_phaseC<<<dim3(64), dim3(256), 0, stream>>>(pre, Ub, Wihb, bih, gi);
    k_gru<<<dim3(1), dim3(768), 0, stream>>>(Whh_h, bhh, gi, h0, tv,
                                             gateW, gateU, gateb, outW, outb, (float*)d_out);
}

// Round 2
// 1957.426 us; speedup vs baseline: 1.0805x; 1.0805x over previous
//
#include <hip/hip_runtime.h>

typedef short short8 __attribute__((ext_vector_type(8)));
typedef float f4 __attribute__((ext_vector_type(4)));
typedef _Float16 half8 __attribute__((ext_vector_type(8)));
typedef _Float16 h2 __attribute__((ext_vector_type(2)));

#define HD 256
#define ED 300
#define EP 320
#define TH 768
#define NS 1024
#define LW 64

__device__ __forceinline__ unsigned short f2bf(float f) {
    unsigned int u = __float_as_uint(f);
    u = (u + 0x7FFFu + ((u >> 16) & 1u)) >> 16;
    return (unsigned short)u;
}
__device__ __forceinline__ float bf2f(unsigned short s) {
    return __uint_as_float(((unsigned int)s) << 16);
}
__device__ __forceinline__ float sigm(float x) { return 1.f / (1.f + __expf(-x)); }
__device__ __forceinline__ float tanh_(float x) {
    x = fminf(fmaxf(x, -15.f), 15.f);
    float e = __expf(2.f * x);
    return (e - 1.f) / (e + 1.f);
}
__device__ __forceinline__ unsigned int pack_h2(float a, float b) {
    h2 p; p.x = (_Float16)a; p.y = (_Float16)b;
    return __builtin_bit_cast(unsigned int, p);
}

__device__ __forceinline__ void load8bf(const unsigned short* p, float* o) {
    uint4 a = *(const uint4*)p;
    o[0] = bf2f((unsigned short)(a.x & 0xffff)); o[1] = bf2f((unsigned short)(a.x >> 16));
    o[2] = bf2f((unsigned short)(a.y & 0xffff)); o[3] = bf2f((unsigned short)(a.y >> 16));
    o[4] = bf2f((unsigned short)(a.z & 0xffff)); o[5] = bf2f((unsigned short)(a.z >> 16));
    o[6] = bf2f((unsigned short)(a.w & 0xffff)); o[7] = bf2f((unsigned short)(a.w >> 16));
}
__device__ __forceinline__ void load4bf(const unsigned short* p, float* o) {
    uint2 a = *(const uint2*)p;
    o[0] = bf2f((unsigned short)(a.x & 0xffff)); o[1] = bf2f((unsigned short)(a.x >> 16));
    o[2] = bf2f((unsigned short)(a.y & 0xffff)); o[3] = bf2f((unsigned short)(a.y >> 16));
}

// ---------------- prep: weight conversions, Dq table, topic vector ----------------
__global__ void k_prep(const float* __restrict__ W, const float* __restrict__ U,
                       const float* __restrict__ Wih, const float* __restrict__ Whh,
                       const float* __restrict__ q, const float* __restrict__ Dm,
                       const float* __restrict__ DT, const float* __restrict__ mlpW,
                       const float* __restrict__ mlpb,
                       unsigned short* __restrict__ Wb, _Float16* __restrict__ Uh,
                       _Float16* __restrict__ Wihh, _Float16* __restrict__ Whhh,
                       float* __restrict__ Dq, float* __restrict__ tv) {
    int bid = blockIdx.x, tid = threadIdx.x;
    if (bid < 768) {
        int r = bid;
        for (int j = tid; j < EP; j += 256)
            Wb[r * EP + j] = (j < ED) ? f2bf(W[r * ED + j]) : (unsigned short)0;
        for (int j = tid; j < HD; j += 256) {
            Uh[r * HD + j] = (_Float16)U[r * HD + j];
            Wihh[r * HD + j] = (_Float16)Wih[r * HD + j];
            Whhh[r * HD + j] = (_Float16)Whh[r * HD + j];
        }
    } else if (bid < 798) {
        int idx = bid - 768;
        int d = idx / 3, part = idx - d * 3;
        int n = part * 256 + tid;
        float s = 0.f;
        for (int h = 0; h < HD; ++h) s += Dm[n * HD + h] * q[d * HD + h];
        Dq[d * TH + n] = s;
    } else {
        if (tid < HD) {
            float s = 0.f;
            for (int k = 0; k < 100; ++k) s += mlpW[tid * 100 + k] * DT[k];
            tv[tid] = tanh_(s + mlpb[tid]);
        }
    }
}

// ---------------- phase B: pre[m][n] = (x @ W^T)[m][n] + Dq_table[dep(m)][n] + b[n] ----------------
__launch_bounds__(256, 2)
__global__ void k_phaseB(const int* __restrict__ sIdx, const int* __restrict__ depT,
                         const float* __restrict__ emb, const unsigned short* __restrict__ Wb,
                         const float* __restrict__ Dq, const float* __restrict__ bias,
                         unsigned short* __restrict__ pre) {
    __shared__ float dq_s[10 * 772];
    __shared__ float b_s[TH];
    __shared__ int dep_s[32];
    __shared__ int idx_s[32];
    int tid = threadIdx.x;
    int c0 = blockIdx.x * 32;
    for (int i = tid; i < 10 * 768; i += 256) {
        int d = i / 768, n = i - d * 768;
        dq_s[d * 772 + n] = Dq[i];
    }
    for (int i = tid; i < TH; i += 256) b_s[i] = bias[i];
    if (tid < 32) {
        int m = c0 + tid;
        idx_s[tid] = sIdx[m];
        int l = m & 63, s = m >> 6;
        dep_s[tid] = (l == 63) ? 9 : depT[s * 63 + l];
    }
    __syncthreads();

    int lane = tid & 63;
    int w = tid >> 6;
    int quad = lane >> 4, l16 = lane & 15;

    const float* xr0 = emb + (long)idx_s[l16] * ED;
    const float* xr1 = emb + (long)idx_s[16 + l16] * ED;

    f4 acc[2][12];
#pragma unroll
    for (int cs = 0; cs < 2; ++cs)
#pragma unroll
        for (int ms = 0; ms < 12; ++ms) acc[cs][ms] = (f4){0.f, 0.f, 0.f, 0.f};

    const unsigned short* wbase = Wb + (w * 192 + l16) * EP;

#pragma unroll
    for (int kt = 0; kt < 10; ++kt) {
        int k0 = kt * 32 + quad * 8;
        short8 bf[2];
#pragma unroll
        for (int cs = 0; cs < 2; ++cs) {
            const float* xr = cs ? xr1 : xr0;
            float xv[8];
            if (k0 + 8 <= ED) {
                float4 f0 = *(const float4*)(xr + k0);
                float4 f1 = *(const float4*)(xr + k0 + 4);
                xv[0] = f0.x; xv[1] = f0.y; xv[2] = f0.z; xv[3] = f0.w;
                xv[4] = f1.x; xv[5] = f1.y; xv[6] = f1.z; xv[7] = f1.w;
            } else {
#pragma unroll
                for (int j = 0; j < 8; ++j) xv[j] = (k0 + j < ED) ? xr[k0 + j] : 0.f;
            }
            short8 t;
#pragma unroll
            for (int j = 0; j < 8; ++j) t[j] = (short)f2bf(xv[j]);
            bf[cs] = t;
        }
#pragma unroll
        for (int ms = 0; ms < 12; ++ms) {
            short8 af = *(const short8*)(wbase + ms * 16 * EP + k0);
            acc[0][ms] = __builtin_amdgcn_mfma_f32_16x16x32_bf16(af, bf[0], acc[0][ms], 0, 0, 0);
            acc[1][ms] = __builtin_amdgcn_mfma_f32_16x16x32_bf16(af, bf[1], acc[1][ms], 0, 0, 0);
        }
    }

#pragma unroll
    for (int cs = 0; cs < 2; ++cs) {
        int xr = c0 + cs * 16 + l16;
        int dep = dep_s[cs * 16 + l16];
        unsigned short* prow = pre + (long)xr * TH;
#pragma unroll
        for (int ms = 0; ms < 12; ++ms) {
            int ncol = w * 192 + ms * 16 + quad * 4;
            f4 dq4 = *(const f4*)&dq_s[dep * 772 + ncol];
            f4 b4 = *(const f4*)&b_s[ncol];
            unsigned int lo = (unsigned int)f2bf(acc[cs][ms][0] + dq4[0] + b4[0]) |
                              ((unsigned int)f2bf(acc[cs][ms][1] + dq4[1] + b4[1]) << 16);
            unsigned int hi = (unsigned int)f2bf(acc[cs][ms][2] + dq4[2] + b4[2]) |
                              ((unsigned int)f2bf(acc[cs][ms][3] + dq4[3] + b4[3]) << 16);
            uint2 v; v.x = lo; v.y = hi;
            *(uint2*)(prow + ncol) = v;
        }
    }
}

// ---------------- phase C v2: U register-resident, 768 threads, 16 sentences/WG ----------------
// Wave w owns output rows [w*64, w*64+64). A = U rows (f16 frags in VGPRs),
// B = h of 16 sentences (LDS hfr, B-frag layout). D[m=U row][n=sentence].
__launch_bounds__(768)
__global__ void k_phaseC(const unsigned short* __restrict__ pre,
                         const _Float16* __restrict__ Uh,
                         const _Float16* __restrict__ Wihh,
                         const float* __restrict__ bih,
                         float* __restrict__ gi) {
    __shared__ __align__(16) uint4 hfr[512];        // [kt][lane] B-fragments of h
    __shared__ __align__(16) float tot[16 * 772];   // [sentence][row] (padded)
    int tid = threadIdx.x;
    int lane = tid & 63, w = tid >> 6, quad = lane >> 4, l16 = lane & 15;
    int s0 = blockIdx.x * 16;

    uint4 frag[32];
    {
        const _Float16* base = Uh + (w * 64 + l16) * HD;
#pragma unroll
        for (int t = 0; t < 4; ++t)
#pragma unroll
            for (int kt = 0; kt < 8; ++kt)
                frag[t * 8 + kt] = *(const uint4*)(base + t * 16 * HD + kt * 32 + quad * 8);
    }

    int us = tid >> 5;           // sentence (tid<512)
    int jg = tid & 31;
    int j0 = jg * 8;
    int hcell = (j0 >> 5) * 64 + 16 * ((j0 >> 3) & 3) + us;
    float hc[8];

    if (tid < 512) {
        const unsigned short* prow = pre + ((long)(s0 + us) * LW + 63) * TH;
        float iv[8], uv[8];
        load8bf(prow + 256 + j0, iv);
        load8bf(prow + 512 + j0, uv);
#pragma unroll
        for (int r = 0; r < 8; ++r) hc[r] = tanh_(sigm(iv[r]) * tanh_(uv[r]));
        uint4 v;
        v.x = pack_h2(hc[0], hc[1]); v.y = pack_h2(hc[2], hc[3]);
        v.z = pack_h2(hc[4], hc[5]); v.w = pack_h2(hc[6], hc[7]);
        hfr[hcell] = v;
    }
    __syncthreads();

    int mb = w * 64 + quad * 4;

    for (int step = 0; step < 63; ++step) {
        int l = 62 - step;
        f4 a0 = (f4){0,0,0,0}, a1 = (f4){0,0,0,0}, a2 = (f4){0,0,0,0}, a3 = (f4){0,0,0,0};
#pragma unroll
        for (int kt = 0; kt < 8; ++kt) {
            half8 b = __builtin_bit_cast(half8, hfr[kt * 64 + lane]);
            a0 = __builtin_amdgcn_mfma_f32_16x16x32_f16(__builtin_bit_cast(half8, frag[kt]), b, a0, 0, 0, 0);
            a1 = __builtin_amdgcn_mfma_f32_16x16x32_f16(__builtin_bit_cast(half8, frag[8 + kt]), b, a1, 0, 0, 0);
            a2 = __builtin_amdgcn_mfma_f32_16x16x32_f16(__builtin_bit_cast(half8, frag[16 + kt]), b, a2, 0, 0, 0);
            a3 = __builtin_amdgcn_mfma_f32_16x16x32_f16(__builtin_bit_cast(half8, frag[24 + kt]), b, a3, 0, 0, 0);
        }
        float* tr = tot + l16 * 772;
        *(f4*)&tr[mb] = a0;
        *(f4*)&tr[mb + 16] = a1;
        *(f4*)&tr[mb + 32] = a2;
        *(f4*)&tr[mb + 48] = a3;
        __syncthreads();
        if (tid < 512) {
            const unsigned short* prow = pre + ((long)(s0 + us) * LW + l) * TH;
            const float* ts = tot + us * 772;
#pragma unroll
            for (int hf = 0; hf < 2; ++hf) {
                int jb = j0 + hf * 4;
                float pf[4], pi_[4], pu[4];
                load4bf(prow + jb, pf);
                load4bf(prow + 256 + jb, pi_);
                load4bf(prow + 512 + jb, pu);
                f4 tf = *(const f4*)&ts[jb];
                f4 ti = *(const f4*)&ts[256 + jb];
                f4 tu = *(const f4*)&ts[512 + jb];
#pragma unroll
                for (int r = 0; r < 4; ++r) {
                    float ff = tf[r] + pf[r];
                    float ii = ti[r] + pi_[r];
                    float uu = tu[r] + pu[r];
                    hc[hf * 4 + r] = tanh_(sigm(ii) * tanh_(uu) + sigm(ff) * hc[hf * 4 + r]);
                }
            }
            uint4 v;
            v.x = pack_h2(hc[0], hc[1]); v.y = pack_h2(hc[2], hc[3]);
            v.z = pack_h2(hc[4], hc[5]); v.w = pack_h2(hc[6], hc[7]);
            hfr[hcell] = v;
        }
        __syncthreads();
    }

    // epilogue: gi[s] = Wih @ sv_s + bih, reuse frag regs for Wih
    {
        const _Float16* base = Wihh + (w * 64 + l16) * HD;
#pragma unroll
        for (int t = 0; t < 4; ++t)
#pragma unroll
            for (int kt = 0; kt < 8; ++kt)
                frag[t * 8 + kt] = *(const uint4*)(base + t * 16 * HD + kt * 32 + quad * 8);
    }
    f4 a0 = (f4){0,0,0,0}, a1 = (f4){0,0,0,0}, a2 = (f4){0,0,0,0}, a3 = (f4){0,0,0,0};
#pragma unroll
    for (int kt = 0; kt < 8; ++kt) {
        half8 b = __builtin_bit_cast(half8, hfr[kt * 64 + lane]);
        a0 = __builtin_amdgcn_mfma_f32_16x16x32_f16(__builtin_bit_cast(half8, frag[kt]), b, a0, 0, 0, 0);
        a1 = __builtin_amdgcn_mfma_f32_16x16x32_f16(__builtin_bit_cast(half8, frag[8 + kt]), b, a1, 0, 0, 0);
        a2 = __builtin_amdgcn_mfma_f32_16x16x32_f16(__builtin_bit_cast(half8, frag[16 + kt]), b, a2, 0, 0, 0);
        a3 = __builtin_amdgcn_mfma_f32_16x16x32_f16(__builtin_bit_cast(half8, frag[24 + kt]), b, a3, 0, 0, 0);
    }
    float* go = gi + (long)(s0 + l16) * TH;
    f4 b0 = *(const f4*)(bih + mb);
    f4 b1 = *(const f4*)(bih + mb + 16);
    f4 b2 = *(const f4*)(bih + mb + 32);
    f4 b3 = *(const f4*)(bih + mb + 48);
    *(f4*)(go + mb) = a0 + b0;
    *(f4*)(go + mb + 16) = a1 + b1;
    *(f4*)(go + mb + 32) = a2 + b2;
    *(f4*)(go + mb + 48) = a3 + b3;
}

// ---------------- GRU v2: Whh register-resident MFMA matvec, 1 WG, 1024 steps + head ----------------
__launch_bounds__(768)
__global__ void k_gru(const _Float16* __restrict__ Whhh, const float* __restrict__ bhh,
                      const float* __restrict__ gi, const float* __restrict__ h0,
                      const float* __restrict__ tv,
                      const float* __restrict__ gateW, const float* __restrict__ gateU,
                      const float* __restrict__ gateb,
                      const float* __restrict__ outW, const float* __restrict__ outb,
                      float* __restrict__ out) {
    __shared__ __align__(16) _Float16 hb[HD];
    __shared__ __align__(16) float ghs[TH];
    __shared__ float hts[HD];
    __shared__ float sgs[512];
    __shared__ float vvs[HD];
    __shared__ float lg[8];

    int tid = threadIdx.x;
    int lane = tid & 63, w = tid >> 6, quad = lane >> 4, l16 = lane & 15;

    uint4 frag[32];
    {
        const _Float16* base = Whhh + (w * 64 + l16) * HD;
#pragma unroll
        for (int t = 0; t < 4; ++t)
#pragma unroll
            for (int kt = 0; kt < 8; ++kt)
                frag[t * 8 + kt] = *(const uint4*)(base + t * 16 * HD + kt * 32 + quad * 8);
    }

    float br = 0.f, bz = 0.f, bn = 0.f, hj = 0.f;
    if (tid < HD) {
        hj = h0[tid];
        hb[tid] = (_Float16)hj;
        br = bhh[tid]; bz = bhh[256 + tid]; bn = bhh[512 + tid];
    }
    __syncthreads();

    int gb = w * 64 + quad * 4;

    for (int t = 0; t < NS; ++t) {
        float gr = 0.f, gz = 0.f, gn = 0.f;
        if (tid < HD) {
            const float* g = gi + (long)t * TH + tid;
            gr = g[0]; gz = g[256]; gn = g[512];
        }
        f4 a0 = (f4){0,0,0,0}, a1 = (f4){0,0,0,0}, a2 = (f4){0,0,0,0}, a3 = (f4){0,0,0,0};
#pragma unroll
        for (int kt = 0; kt < 8; ++kt) {
            half8 b = __builtin_bit_cast(half8, *(const uint4*)&hb[kt * 32 + quad * 8]);
            a0 = __builtin_amdgcn_mfma_f32_16x16x32_f16(__builtin_bit_cast(half8, frag[kt]), b, a0, 0, 0, 0);
            a1 = __builtin_amdgcn_mfma_f32_16x16x32_f16(__builtin_bit_cast(half8, frag[8 + kt]), b, a1, 0, 0, 0);
            a2 = __builtin_amdgcn_mfma_f32_16x16x32_f16(__builtin_bit_cast(half8, frag[16 + kt]), b, a2, 0, 0, 0);
            a3 = __builtin_amdgcn_mfma_f32_16x16x32_f16(__builtin_bit_cast(half8, frag[24 + kt]), b, a3, 0, 0, 0);
        }
        if (l16 == 0) {
            *(f4*)&ghs[gb] = a0;
            *(f4*)&ghs[gb + 16] = a1;
            *(f4*)&ghs[gb + 32] = a2;
            *(f4*)&ghs[gb + 48] = a3;
        }
        __syncthreads();
        if (tid < HD) {
            float r = sigm(gr + ghs[tid] + br);
            float z = sigm(gz + ghs[256 + tid] + bz);
            float n = tanh_(gn + r * (ghs[512 + tid] + bn));
            hj = (1.f - z) * n + z * hj;
            hb[tid] = (_Float16)hj;
        }
        __syncthreads();
    }

    // head
    if (tid < HD) hts[tid] = hj;
    __syncthreads();
    if (tid < 512) {
        float s = gateb[tid];
        for (int k = 0; k < HD; ++k)
            s += gateW[tid * HD + k] * hts[k] + gateU[tid * HD + k] * tv[k];
        sgs[tid] = sigm(s);
    }
    __syncthreads();
    if (tid < HD) vvs[tid] = tanh_(sgs[tid] * hts[tid] + sgs[256 + tid] * tv[tid]);
    __syncthreads();
    if (tid < 5) {
        float s = outb[tid];
        for (int k = 0; k < HD; ++k) s += outW[tid * HD + k] * vvs[k];
        lg[tid] = s;
    }
    __syncthreads();
    if (tid == 0) {
        float m = lg[0];
        for (int i = 1; i < 5; ++i) m = fmaxf(m, lg[i]);
        float e[5], sum = 0.f;
        for (int i = 0; i < 5; ++i) { e[i] = __expf(lg[i] - m); sum += e[i]; }
        for (int i = 0; i < 5; ++i) out[i] = e[i] / sum;
    }
}

extern "C" void kernel_launch(void* const* d_in, const int* in_sizes, int n_in,
                              void* d_out, int out_size, void* d_ws, size_t ws_size,
                              hipStream_t stream) {
    (void)in_sizes; (void)n_in; (void)out_size; (void)ws_size;
    const int* sIdx = (const int*)d_in[0];
    const int* depT = (const int*)d_in[1];
    const float* DT = (const float*)d_in[2];
    const float* h0 = (const float*)d_in[3];
    const float* emb = (const float*)d_in[4];
    const float* q = (const float*)d_in[5];
    const float* W = (const float*)d_in[6];
    const float* U = (const float*)d_in[7];
    const float* Dm = (const float*)d_in[8];
    const float* b = (const float*)d_in[9];
    const float* Wih = (const float*)d_in[10];
    const float* Whh = (const float*)d_in[11];
    const float* bih = (const float*)d_in[12];
    const float* bhh = (const float*)d_in[13];
    const float* gateW = (const float*)d_in[14];
    const float* gateU = (const float*)d_in[15];
    const float* gateb = (const float*)d_in[16];
    const float* mlpW = (const float*)d_in[17];
    const float* mlpb = (const float*)d_in[18];
    const float* outW = (const float*)d_in[19];
    const float* outb = (const float*)d_in[20];

    char* ws = (char*)d_ws;
    unsigned short* Wb = (unsigned short*)ws;   ws += 768 * 320 * 2;
    _Float16* Uh = (_Float16*)ws;               ws += 768 * 256 * 2;
    _Float16* Wihh = (_Float16*)ws;             ws += 768 * 256 * 2;
    _Float16* Whhh = (_Float16*)ws;             ws += 768 * 256 * 2;
    float* Dq = (float*)ws;                     ws += 10 * 768 * 4;
    float* tv = (float*)ws;                     ws += 1024;
    ws = (char*)d_ws + ((((size_t)(ws - (char*)d_ws)) + 4095) & ~(size_t)4095);
    unsigned short* pre = (unsigned short*)ws;  ws += (size_t)65536 * 768 * 2;
    float* gi = (float*)ws;                     ws += (size_t)1024 * 768 * 4;

    k_prep<<<dim3(799), dim3(256), 0, stream>>>(W, U, Wih, Whh, q, Dm, DT, mlpW, mlpb,
                                                Wb, Uh, Wihh, Whhh, Dq, tv);
    k_phaseB<<<dim3(2048), dim3(256), 0, stream>>>(sIdx, depT, emb, Wb, Dq, b, pre);
    k_phaseC<<<dim3(64), dim3(768), 0, stream>>>(pre, Uh, Wihh, bih, gi);
    k_gru<<<dim3(1), dim3(768), 0, stream>>>(Whhh, bhh, gi, h0, tv,
                                             gateW, gateU, gateb, outW, outb, (float*)d_out);
}